// Round 1
// baseline (1048.448 us; speedup 1.0000x reference)
//
#include <hip/hip_runtime.h>
#include <stdint.h>
#include <math.h>

// Problem constants
#define N_SEQ 4096
#define EDIM  2048
#define NH    16
#define HD    128

typedef __attribute__((ext_vector_type(8))) short bf16x8;
typedef __attribute__((ext_vector_type(4))) float f32x4;

__device__ __forceinline__ unsigned short f2bf(float f) {
    union { float f; unsigned u; } v; v.f = f;
    unsigned r = v.u + 0x7FFFu + ((v.u >> 16) & 1u);
    return (unsigned short)(r >> 16);
}
__device__ __forceinline__ float bf2f(unsigned short h) {
    union { unsigned u; float f; } v; v.u = ((unsigned)h) << 16;
    return v.f;
}

// ---------------------------------------------------------------- convert x
__global__ void k_convert_x(const float* __restrict__ x,
                            unsigned short* __restrict__ xb, int n4) {
    int i = blockIdx.x * blockDim.x + threadIdx.x;
    int stride = gridDim.x * blockDim.x;
    for (; i < n4; i += stride) {
        float4 v = ((const float4*)x)[i];
        ushort4 o;
        o.x = f2bf(v.x); o.y = f2bf(v.y); o.z = f2bf(v.z); o.w = f2bf(v.w);
        ((ushort4*)xb)[i] = o;
    }
}

// ---------------------------------------------- transpose f32 (RxC) -> bf16 (CxR)
__global__ void k_transpose_f32_bf16(const float* __restrict__ in,
                                     unsigned short* __restrict__ out,
                                     int R, int C) {
    __shared__ unsigned short Ls[64][68];
    const int c0 = blockIdx.x * 64, r0 = blockIdx.y * 64;
    const int t = threadIdx.x;
    #pragma unroll
    for (int i = 0; i < 4; ++i) {
        int ch = i * 256 + t;              // 1024 float4 chunks
        int r = ch >> 4, c4 = (ch & 15) * 4;
        float4 v = *(const float4*)&in[(size_t)(r0 + r) * C + c0 + c4];
        ushort4 o;
        o.x = f2bf(v.x); o.y = f2bf(v.y); o.z = f2bf(v.z); o.w = f2bf(v.w);
        *(ushort4*)&Ls[r][c4] = o;
    }
    __syncthreads();
    #pragma unroll
    for (int i = 0; i < 2; ++i) {
        int ch = i * 256 + t;              // 512 chunks of 8 bf16
        int rr = ch >> 3, c8 = (ch & 7) * 8;
        unsigned short vals[8];
        #pragma unroll
        for (int j = 0; j < 8; ++j) vals[j] = Ls[c8 + j][rr];
        uint4 pk;
        pk.x = (unsigned)vals[0] | ((unsigned)vals[1] << 16);
        pk.y = (unsigned)vals[2] | ((unsigned)vals[3] << 16);
        pk.z = (unsigned)vals[4] | ((unsigned)vals[5] << 16);
        pk.w = (unsigned)vals[6] | ((unsigned)vals[7] << 16);
        *(uint4*)&out[(size_t)(c0 + rr) * R + r0 + c8] = pk;
    }
}

// ---------------------------------------------------------------- bt GEMM
// C[M,N] = A[M,K] * Bt[N,K]^T  (bf16 in, f32 acc, bf16 or f32 out)
template<int F32OUT>
__launch_bounds__(256, 2)
__global__ void k_gemm_bt(const unsigned short* __restrict__ A,
                          const unsigned short* __restrict__ Bt,
                          void* __restrict__ C,
                          int M, int N, int K) {
    __shared__ unsigned short As[128][72];
    __shared__ unsigned short Bs[128][72];
    const int t = threadIdx.x;
    const int wave = t >> 6, lane = t & 63;
    const int wm = wave >> 1, wn = wave & 1;
    const int lg = lane >> 4, lr = lane & 15;
    const int m0 = blockIdx.y * 128, n0 = blockIdx.x * 128;

    f32x4 acc[4][4];
    #pragma unroll
    for (int i = 0; i < 4; ++i)
        #pragma unroll
        for (int j = 0; j < 4; ++j) acc[i][j] = f32x4{0.f, 0.f, 0.f, 0.f};

    const int nkb = K >> 6;
    for (int kb = 0; kb < nkb; ++kb) {
        uint4 ar[4], br[4];
        #pragma unroll
        for (int i = 0; i < 4; ++i) {
            int ch = i * 256 + t;
            int row = ch >> 3, k8 = (ch & 7) * 8;
            ar[i] = *(const uint4*)&A [(size_t)(m0 + row) * K + kb * 64 + k8];
            br[i] = *(const uint4*)&Bt[(size_t)(n0 + row) * K + kb * 64 + k8];
        }
        __syncthreads();
        #pragma unroll
        for (int i = 0; i < 4; ++i) {
            int ch = i * 256 + t;
            int row = ch >> 3, k8 = (ch & 7) * 8;
            *(uint4*)&As[row][k8] = ar[i];
            *(uint4*)&Bs[row][k8] = br[i];
        }
        __syncthreads();
        #pragma unroll
        for (int kk = 0; kk < 2; ++kk) {
            bf16x8 af[4], bf[4];
            #pragma unroll
            for (int i = 0; i < 4; ++i) {
                af[i] = *(const bf16x8*)&As[wm * 64 + i * 16 + lr][kk * 32 + lg * 8];
                bf[i] = *(const bf16x8*)&Bs[wn * 64 + i * 16 + lr][kk * 32 + lg * 8];
            }
            #pragma unroll
            for (int i = 0; i < 4; ++i)
                #pragma unroll
                for (int j = 0; j < 4; ++j)
                    acc[i][j] = __builtin_amdgcn_mfma_f32_16x16x32_bf16(af[i], bf[j], acc[i][j], 0, 0, 0);
        }
    }
    #pragma unroll
    for (int i = 0; i < 4; ++i) {
        int row0 = m0 + wm * 64 + i * 16 + lg * 4;
        #pragma unroll
        for (int j = 0; j < 4; ++j) {
            int col = n0 + wn * 64 + j * 16 + lr;
            #pragma unroll
            for (int r = 0; r < 4; ++r) {
                if (F32OUT)
                    ((float*)C)[(size_t)(row0 + r) * N + col] = acc[i][j][r];
                else
                    ((unsigned short*)C)[(size_t)(row0 + r) * N + col] = f2bf(acc[i][j][r]);
            }
        }
    }
}

// ------------------------------------------------------- RoPE + LayerNorm (q,k)
// proj: [N_SEQ][3*EDIM] bf16. Writes Qh,Kh: [NH][N_SEQ][HD] bf16.
__global__ void k_ropeln(const unsigned short* __restrict__ proj,
                         const float* __restrict__ ln_scale,
                         const float* __restrict__ ln_bias,
                         unsigned short* __restrict__ Qh,
                         unsigned short* __restrict__ Kh) {
    const int n = blockIdx.x;
    const int wave = threadIdx.x >> 6, lane = threadIdx.x & 63;
    // inv_freq = 10000^(-2*lane/128)
    float inv = expf(-((float)(2 * lane) / 128.0f) * 9.210340371976184f);
    float ang = (float)n * inv;
    float c = cosf(ang), s = sinf(ang);
    const float sc1 = ln_scale[lane], sc2 = ln_scale[lane + 64];
    const float b1 = ln_bias[lane],  b2 = ln_bias[lane + 64];

    for (int r = wave; r < 32; r += 4) {
        int h = r >> 1, qk = r & 1;
        const unsigned short* src = proj + (size_t)n * (3 * EDIM) + qk * EDIM + h * HD;
        float x1 = bf2f(src[lane]), x2 = bf2f(src[lane + 64]);
        float o1 = x1 * c - x2 * s;
        float o2 = x1 * s + x2 * c;
        float sum = o1 + o2, sq = o1 * o1 + o2 * o2;
        #pragma unroll
        for (int d = 1; d < 64; d <<= 1) {
            sum += __shfl_xor(sum, d);
            sq  += __shfl_xor(sq, d);
        }
        float mean = sum * (1.0f / 128.0f);
        float var = sq * (1.0f / 128.0f) - mean * mean;
        float rstd = rsqrtf(var + 1e-5f);
        float y1 = (o1 - mean) * rstd * sc1 + b1;
        float y2 = (o2 - mean) * rstd * sc2 + b2;
        unsigned short* dst = (qk ? Kh : Qh) + ((size_t)h * N_SEQ + n) * HD;
        dst[lane]      = f2bf(y1);
        dst[lane + 64] = f2bf(y2);
    }
}

// ---------------------------------------------------- V transpose: [n][d] -> [d][n]
__global__ void k_vtrans(const unsigned short* __restrict__ proj,
                         unsigned short* __restrict__ Vt) {
    __shared__ unsigned short Ls[64][136];
    const int h = blockIdx.y;
    const int n0 = blockIdx.x * 64;
    const int t = threadIdx.x;
    #pragma unroll
    for (int i = 0; i < 4; ++i) {
        int ch = i * 256 + t;              // 1024 chunks: 64 n-rows x 16 d-chunks
        int r = ch >> 4, d0 = (ch & 15) * 8;
        uint4 v = *(const uint4*)&proj[(size_t)(n0 + r) * (3 * EDIM) + 2 * EDIM + h * HD + d0];
        *(uint4*)&Ls[r][d0] = v;
    }
    __syncthreads();
    #pragma unroll
    for (int i = 0; i < 4; ++i) {
        int ch = i * 256 + t;              // 1024 chunks: 128 d-rows x 8 n-chunks
        int d = ch >> 3, nb = (ch & 7) * 8;
        unsigned short vals[8];
        #pragma unroll
        for (int j = 0; j < 8; ++j) vals[j] = Ls[nb + j][d];
        uint4 pk;
        pk.x = (unsigned)vals[0] | ((unsigned)vals[1] << 16);
        pk.y = (unsigned)vals[2] | ((unsigned)vals[3] << 16);
        pk.z = (unsigned)vals[4] | ((unsigned)vals[5] << 16);
        pk.w = (unsigned)vals[6] | ((unsigned)vals[7] << 16);
        *(uint4*)&Vt[((size_t)h * HD + d) * N_SEQ + n0 + nb] = pk;
    }
}

// ------------------------------------------------------- polynomial attention
// Qh,Kh: [NH][N_SEQ][HD], Vt: [NH][HD][N_SEQ]. O: [N_SEQ][EDIM] bf16 (n-major).
__launch_bounds__(256, 2)
__global__ void k_attn(const unsigned short* __restrict__ Qh,
                       const unsigned short* __restrict__ Kh,
                       const unsigned short* __restrict__ Vt,
                       unsigned short* __restrict__ O) {
    __shared__ unsigned short Ks[64][136];
    __shared__ unsigned short Vs[128][72];
    __shared__ unsigned short Ps[128][72];

    const int h = blockIdx.y;
    const int qb = gridDim.x - 1 - blockIdx.x;   // heavy blocks first
    const int q0 = qb * 128;
    const int t = threadIdx.x;
    const int wave = t >> 6, lane = t & 63;
    const int wm = wave >> 1, wn = wave & 1;
    const int lg = lane >> 4, lr = lane & 15;

    // Q fragments in registers (wave's 64 queries x 128 d)
    bf16x8 qf[4][4];
    #pragma unroll
    for (int mi = 0; mi < 4; ++mi)
        #pragma unroll
        for (int kk = 0; kk < 4; ++kk)
            qf[mi][kk] = *(const bf16x8*)&Qh[((size_t)h * N_SEQ + q0 + wm * 64 + mi * 16 + lr) * HD + kk * 32 + lg * 8];

    f32x4 acc[4][4];
    #pragma unroll
    for (int i = 0; i < 4; ++i)
        #pragma unroll
        for (int j = 0; j < 4; ++j) acc[i][j] = f32x4{0.f, 0.f, 0.f, 0.f};
    f32x4 accd[4];
    #pragma unroll
    for (int i = 0; i < 4; ++i) accd[i] = f32x4{0.f, 0.f, 0.f, 0.f};

    // ones B-fragment: V[k][col]=1 for col==0 -> row-sum in output col 0
    bf16x8 onesf;
    {
        short ov = (lr == 0) ? (short)0x3F80 : (short)0;
        #pragma unroll
        for (int j = 0; j < 8; ++j) onesf[j] = ov;
    }

    const int nkb = 2 * qb + 2;
    for (int kb = 0; kb < nkb; ++kb) {
        const int k0 = kb * 64;
        uint4 kr[4], vr[4];
        #pragma unroll
        for (int i = 0; i < 4; ++i) {
            int ch = i * 256 + t;
            { int r = ch >> 4, d0 = (ch & 15) * 8;
              kr[i] = *(const uint4*)&Kh[((size_t)h * N_SEQ + k0 + r) * HD + d0]; }
            { int d = ch >> 3, n8 = (ch & 7) * 8;
              vr[i] = *(const uint4*)&Vt[((size_t)h * HD + d) * N_SEQ + k0 + n8]; }
        }
        __syncthreads();   // previous PV reads done
        #pragma unroll
        for (int i = 0; i < 4; ++i) {
            int ch = i * 256 + t;
            { int r = ch >> 4, d0 = (ch & 15) * 8; *(uint4*)&Ks[r][d0] = kr[i]; }
            { int d = ch >> 3, n8 = (ch & 7) * 8;  *(uint4*)&Vs[d][n8] = vr[i]; }
        }
        __syncthreads();

        // ---- S = Q K^T, mask, ^4, write P to LDS
        bf16x8 kf[2][4];
        #pragma unroll
        for (int ni = 0; ni < 2; ++ni)
            #pragma unroll
            for (int kk = 0; kk < 4; ++kk)
                kf[ni][kk] = *(const bf16x8*)&Ks[wn * 32 + ni * 16 + lr][kk * 32 + lg * 8];
        #pragma unroll
        for (int mi = 0; mi < 4; ++mi) {
            f32x4 sa0 = f32x4{0.f, 0.f, 0.f, 0.f};
            f32x4 sa1 = f32x4{0.f, 0.f, 0.f, 0.f};
            #pragma unroll
            for (int kk = 0; kk < 4; ++kk) {
                sa0 = __builtin_amdgcn_mfma_f32_16x16x32_bf16(qf[mi][kk], kf[0][kk], sa0, 0, 0, 0);
                sa1 = __builtin_amdgcn_mfma_f32_16x16x32_bf16(qf[mi][kk], kf[1][kk], sa1, 0, 0, 0);
            }
            int gk0 = k0 + wn * 32 + lr;
            int gk1 = gk0 + 16;
            #pragma unroll
            for (int r = 0; r < 4; ++r) {
                int rowl = wm * 64 + mi * 16 + lg * 4 + r;
                int gq = q0 + rowl;
                float s0 = sa0[r], s1 = sa1[r];
                float t0 = s0 * s0, t1 = s1 * s1;
                float p0 = (gk0 <= gq) ? t0 * t0 : 0.0f;
                float p1 = (gk1 <= gq) ? t1 * t1 : 0.0f;
                Ps[rowl][wn * 32 + lr]      = f2bf(p0);
                Ps[rowl][wn * 32 + 16 + lr] = f2bf(p1);
            }
        }
        __syncthreads();   // P visible to all waves

        // ---- O += P V,  denom += P * ones
        #pragma unroll
        for (int kk = 0; kk < 2; ++kk) {
            bf16x8 pf[4], vf[4];
            #pragma unroll
            for (int mi = 0; mi < 4; ++mi)
                pf[mi] = *(const bf16x8*)&Ps[wm * 64 + mi * 16 + lr][kk * 32 + lg * 8];
            #pragma unroll
            for (int ni = 0; ni < 4; ++ni)
                vf[ni] = *(const bf16x8*)&Vs[wn * 64 + ni * 16 + lr][kk * 32 + lg * 8];
            #pragma unroll
            for (int mi = 0; mi < 4; ++mi) {
                #pragma unroll
                for (int ni = 0; ni < 4; ++ni)
                    acc[mi][ni] = __builtin_amdgcn_mfma_f32_16x16x32_bf16(pf[mi], vf[ni], acc[mi][ni], 0, 0, 0);
                accd[mi] = __builtin_amdgcn_mfma_f32_16x16x32_bf16(pf[mi], onesf, accd[mi], 0, 0, 0);
            }
        }
    }

    // epilogue: out = acc / denom
    #pragma unroll
    for (int mi = 0; mi < 4; ++mi) {
        #pragma unroll
        for (int r = 0; r < 4; ++r) {
            float dv = __shfl(accd[mi][r], lane & 48);  // from lane lg*16 (col 0)
            float rinv = 1.0f / dv;
            int gq = q0 + wm * 64 + mi * 16 + lg * 4 + r;
            #pragma unroll
            for (int ni = 0; ni < 4; ++ni) {
                int dcol = wn * 64 + ni * 16 + lr;
                O[(size_t)gq * EDIM + h * HD + dcol] = f2bf(acc[mi][ni][r] * rinv);
            }
        }
    }
}

// ---------------------------------------------------------------- launch
extern "C" void kernel_launch(void* const* d_in, const int* in_sizes, int n_in,
                              void* d_out, int out_size, void* d_ws, size_t ws_size,
                              hipStream_t stream) {
    const float* x        = (const float*)d_in[0];
    const float* w_qkv    = (const float*)d_in[1];
    const float* w_out    = (const float*)d_in[2];
    const float* ln_scale = (const float*)d_in[3];
    const float* ln_bias  = (const float*)d_in[4];

    if (ws_size < 134217728u) return;  // need 128 MiB

    char* ws = (char*)d_ws;
    // lifetime-aliased layout (128 MiB total):
    unsigned short* xb    = (unsigned short*)(ws);              // 16 MiB; reused as attnO
    unsigned short* wqkvT = (unsigned short*)(ws + 16777216);   // 24 MiB; reused as Qh
    unsigned short* woutT = (unsigned short*)(ws + 41943040);   //  8 MiB
    unsigned short* proj  = (unsigned short*)(ws + 50331648);   // 48 MiB
    unsigned short* Kh    = (unsigned short*)(ws + 100663296);  // 16 MiB
    unsigned short* Vt    = (unsigned short*)(ws + 117440512);  // 16 MiB
    unsigned short* Qh    = wqkvT;   // alias: w_qkvT dead after GEMM1
    unsigned short* attnO = xb;      // alias: xb dead after GEMM1

    k_convert_x<<<2048, 256, 0, stream>>>(x, xb, (N_SEQ * EDIM) / 4);
    k_transpose_f32_bf16<<<dim3(3 * EDIM / 64, EDIM / 64), 256, 0, stream>>>(w_qkv, wqkvT, EDIM, 3 * EDIM);
    k_transpose_f32_bf16<<<dim3(EDIM / 64, EDIM / 64), 256, 0, stream>>>(w_out, woutT, EDIM, EDIM);
    k_gemm_bt<0><<<dim3(3 * EDIM / 128, N_SEQ / 128), 256, 0, stream>>>(xb, wqkvT, proj, N_SEQ, 3 * EDIM, EDIM);
    k_ropeln<<<N_SEQ, 256, 0, stream>>>(proj, ln_scale, ln_bias, Qh, Kh);
    k_vtrans<<<dim3(N_SEQ / 64, NH), 256, 0, stream>>>(proj, Vt);
    k_attn<<<dim3(N_SEQ / 128, NH), 256, 0, stream>>>(Qh, Kh, Vt, attnO);
    k_gemm_bt<1><<<dim3(EDIM / 128, N_SEQ / 128), 256, 0, stream>>>(attnO, woutT, (float*)d_out, N_SEQ, EDIM, EDIM);
}

// Round 2
// 517.103 us; speedup vs baseline: 2.0275x; 2.0275x over previous
//
#include <hip/hip_runtime.h>
#include <stdint.h>
#include <math.h>

// Problem constants
#define N_SEQ 4096
#define EDIM  2048
#define NH    16
#define HD    128

typedef __attribute__((ext_vector_type(8))) short bf16x8;
typedef __attribute__((ext_vector_type(4))) float f32x4;

#define AS1 __attribute__((address_space(1)))
#define AS3 __attribute__((address_space(3)))

__device__ __forceinline__ void gll16(const unsigned short* g, unsigned short* l) {
    __builtin_amdgcn_global_load_lds((const AS1 unsigned int*)g,
                                     (AS3 unsigned int*)l, 16, 0, 0);
}

__device__ __forceinline__ unsigned short f2bf(float f) {
    union { float f; unsigned u; } v; v.f = f;
    unsigned r = v.u + 0x7FFFu + ((v.u >> 16) & 1u);
    return (unsigned short)(r >> 16);
}
__device__ __forceinline__ float bf2f(unsigned short h) {
    union { unsigned u; float f; } v; v.u = ((unsigned)h) << 16;
    return v.f;
}

// ---------------------------------------------------------------- convert x
__global__ void k_convert_x(const float* __restrict__ x,
                            unsigned short* __restrict__ xb, int n4) {
    int i = blockIdx.x * blockDim.x + threadIdx.x;
    int stride = gridDim.x * blockDim.x;
    for (; i < n4; i += stride) {
        float4 v = ((const float4*)x)[i];
        ushort4 o;
        o.x = f2bf(v.x); o.y = f2bf(v.y); o.z = f2bf(v.z); o.w = f2bf(v.w);
        ((ushort4*)xb)[i] = o;
    }
}

// ---------------------------------------------- transpose f32 (RxC) -> bf16 (CxR)
__global__ void k_transpose_f32_bf16(const float* __restrict__ in,
                                     unsigned short* __restrict__ out,
                                     int R, int C) {
    __shared__ unsigned short Ls[64][68];
    const int c0 = blockIdx.x * 64, r0 = blockIdx.y * 64;
    const int t = threadIdx.x;
    #pragma unroll
    for (int i = 0; i < 4; ++i) {
        int ch = i * 256 + t;              // 1024 float4 chunks
        int r = ch >> 4, c4 = (ch & 15) * 4;
        float4 v = *(const float4*)&in[(size_t)(r0 + r) * C + c0 + c4];
        ushort4 o;
        o.x = f2bf(v.x); o.y = f2bf(v.y); o.z = f2bf(v.z); o.w = f2bf(v.w);
        *(ushort4*)&Ls[r][c4] = o;
    }
    __syncthreads();
    #pragma unroll
    for (int i = 0; i < 2; ++i) {
        int ch = i * 256 + t;              // 512 chunks of 8 bf16
        int rr = ch >> 3, c8 = (ch & 7) * 8;
        unsigned short vals[8];
        #pragma unroll
        for (int j = 0; j < 8; ++j) vals[j] = Ls[c8 + j][rr];
        uint4 pk;
        pk.x = (unsigned)vals[0] | ((unsigned)vals[1] << 16);
        pk.y = (unsigned)vals[2] | ((unsigned)vals[3] << 16);
        pk.z = (unsigned)vals[4] | ((unsigned)vals[5] << 16);
        pk.w = (unsigned)vals[6] | ((unsigned)vals[7] << 16);
        *(uint4*)&out[(size_t)(c0 + rr) * R + r0 + c8] = pk;
    }
}

// ---------------------------------------------------------------- bt GEMM
// C[M,N] = A[M,K] * Bt[N,K]^T  (bf16 in, f32 acc, bf16 or f32 out)
// m97 structure: global_load_lds(16B) staging, linear LDS + XOR-swizzled
// source/read (rule #21), 2 barriers per K-step, XCD-swizzled block id.
template<int F32OUT>
__launch_bounds__(256, 2)
__global__ void k_gemm_bt(const unsigned short* __restrict__ A,
                          const unsigned short* __restrict__ Bt,
                          void* __restrict__ C,
                          int M, int N, int K) {
    __shared__ unsigned short sh[2 * 128 * 64];   // As | Bs, linear [128][64]
    unsigned short* As = sh;
    unsigned short* Bs = sh + 128 * 64;

    const int t = threadIdx.x;
    const int wave = t >> 6, lane = t & 63;
    const int wm = wave >> 1, wn = wave & 1;
    const int lg = lane >> 4, lr = lane & 15;

    // XCD-aware bijective swizzle (nwg % 8 == 0 for all our grids)
    const int nbx = gridDim.x;
    const int nwg = nbx * gridDim.y;
    int bid = blockIdx.y * nbx + blockIdx.x;
    int swz = (bid & 7) * (nwg >> 3) + (bid >> 3);
    const int m0 = (swz / nbx) * 128;
    const int n0 = (swz % nbx) * 128;

    const unsigned short* aptr = A  + (size_t)m0 * K;
    const unsigned short* bptr = Bt + (size_t)n0 * K;

    f32x4 acc[4][4];
    #pragma unroll
    for (int i = 0; i < 4; ++i)
        #pragma unroll
        for (int j = 0; j < 4; ++j) acc[i][j] = f32x4{0.f, 0.f, 0.f, 0.f};

    // per-thread staging geometry (loop-invariant)
    int schr[4], srow[4], scb[4];
    #pragma unroll
    for (int i = 0; i < 4; ++i) {
        int ch = (i * 4 + wave) * 64 + lane;   // 0..1023, wave-uniform base + lane
        schr[i] = ch;
        srow[i] = ch >> 3;
        scb[i]  = (ch & 7) ^ ((ch >> 3) & 7);  // inverse-swizzled source col-block
    }

    const int nkb = K >> 6;
    for (int kb = 0; kb < nkb; ++kb) {
        __syncthreads();   // previous iter's ds_reads done before overwrite
        #pragma unroll
        for (int i = 0; i < 4; ++i) {
            const size_t goff = (size_t)srow[i] * K + (size_t)kb * 64 + scb[i] * 8;
            gll16(&aptr[goff], &As[schr[i] * 8]);
            gll16(&bptr[goff], &Bs[schr[i] * 8]);
        }
        __syncthreads();   // drains vmcnt+lgkm (compiler-inserted before barrier)

        #pragma unroll
        for (int kk = 0; kk < 2; ++kk) {
            bf16x8 af[4], bf[4];
            const int cbx = ((kk * 4 + lg) ^ (lr & 7)) * 8;  // swizzled read col
            #pragma unroll
            for (int i = 0; i < 4; ++i) {
                af[i] = *(const bf16x8*)&As[(wm * 64 + i * 16 + lr) * 64 + cbx];
                bf[i] = *(const bf16x8*)&Bs[(wn * 64 + i * 16 + lr) * 64 + cbx];
            }
            #pragma unroll
            for (int i = 0; i < 4; ++i)
                #pragma unroll
                for (int j = 0; j < 4; ++j)
                    acc[i][j] = __builtin_amdgcn_mfma_f32_16x16x32_bf16(af[i], bf[j], acc[i][j], 0, 0, 0);
        }
    }

    if (F32OUT) {
        // f32 scattered stores already cover full 64B lines (16 lanes x 4B)
        #pragma unroll
        for (int i = 0; i < 4; ++i) {
            int row0 = m0 + wm * 64 + i * 16 + lg * 4;
            #pragma unroll
            for (int j = 0; j < 4; ++j) {
                int col = n0 + wn * 64 + j * 16 + lr;
                #pragma unroll
                for (int r = 0; r < 4; ++r)
                    ((float*)C)[(size_t)(row0 + r) * N + col] = acc[i][j][r];
            }
        }
    } else {
        // stage bf16 C-tile in LDS, write out coalesced uint4 rows
        __syncthreads();
        unsigned short* Cs = sh;     // [128][128]
        #pragma unroll
        for (int i = 0; i < 4; ++i) {
            #pragma unroll
            for (int j = 0; j < 4; ++j) {
                int col = wn * 64 + j * 16 + lr;
                #pragma unroll
                for (int r = 0; r < 4; ++r)
                    Cs[(wm * 64 + i * 16 + lg * 4 + r) * 128 + col] = f2bf(acc[i][j][r]);
            }
        }
        __syncthreads();
        #pragma unroll
        for (int i = 0; i < 8; ++i) {
            int ch = i * 256 + t;             // 2048 chunks of 8 shorts
            int row = ch >> 4, c8 = (ch & 15) * 8;
            *(uint4*)&((unsigned short*)C)[(size_t)(m0 + row) * N + n0 + c8] =
                *(const uint4*)&Cs[row * 128 + c8];
        }
    }
}

// ------------------------------------------------------- RoPE + LayerNorm (q,k)
// proj: [N_SEQ][3*EDIM] bf16. Writes Qh,Kh: [NH][N_SEQ][HD] bf16.
__global__ void k_ropeln(const unsigned short* __restrict__ proj,
                         const float* __restrict__ ln_scale,
                         const float* __restrict__ ln_bias,
                         unsigned short* __restrict__ Qh,
                         unsigned short* __restrict__ Kh) {
    const int n = blockIdx.x;
    const int wave = threadIdx.x >> 6, lane = threadIdx.x & 63;
    float inv = expf(-((float)(2 * lane) / 128.0f) * 9.210340371976184f);
    float ang = (float)n * inv;
    float c = cosf(ang), s = sinf(ang);
    const float sc1 = ln_scale[lane], sc2 = ln_scale[lane + 64];
    const float b1 = ln_bias[lane],  b2 = ln_bias[lane + 64];

    for (int r = wave; r < 32; r += 4) {
        int h = r >> 1, qk = r & 1;
        const unsigned short* src = proj + (size_t)n * (3 * EDIM) + qk * EDIM + h * HD;
        float x1 = bf2f(src[lane]), x2 = bf2f(src[lane + 64]);
        float o1 = x1 * c - x2 * s;
        float o2 = x1 * s + x2 * c;
        float sum = o1 + o2, sq = o1 * o1 + o2 * o2;
        #pragma unroll
        for (int d = 1; d < 64; d <<= 1) {
            sum += __shfl_xor(sum, d);
            sq  += __shfl_xor(sq, d);
        }
        float mean = sum * (1.0f / 128.0f);
        float var = sq * (1.0f / 128.0f) - mean * mean;
        float rstd = rsqrtf(var + 1e-5f);
        float y1 = (o1 - mean) * rstd * sc1 + b1;
        float y2 = (o2 - mean) * rstd * sc2 + b2;
        unsigned short* dst = (qk ? Kh : Qh) + ((size_t)h * N_SEQ + n) * HD;
        dst[lane]      = f2bf(y1);
        dst[lane + 64] = f2bf(y2);
    }
}

// ---------------------------------------------------- V transpose: [n][d] -> [d][n]
__global__ void k_vtrans(const unsigned short* __restrict__ proj,
                         unsigned short* __restrict__ Vt) {
    __shared__ unsigned short Ls[64][136];
    const int h = blockIdx.y;
    const int n0 = blockIdx.x * 64;
    const int t = threadIdx.x;
    #pragma unroll
    for (int i = 0; i < 4; ++i) {
        int ch = i * 256 + t;              // 1024 chunks: 64 n-rows x 16 d-chunks
        int r = ch >> 4, d0 = (ch & 15) * 8;
        uint4 v = *(const uint4*)&proj[(size_t)(n0 + r) * (3 * EDIM) + 2 * EDIM + h * HD + d0];
        *(uint4*)&Ls[r][d0] = v;
    }
    __syncthreads();
    #pragma unroll
    for (int i = 0; i < 4; ++i) {
        int ch = i * 256 + t;              // 1024 chunks: 128 d-rows x 8 n-chunks
        int d = ch >> 3, nb = (ch & 7) * 8;
        unsigned short vals[8];
        #pragma unroll
        for (int j = 0; j < 8; ++j) vals[j] = Ls[nb + j][d];
        uint4 pk;
        pk.x = (unsigned)vals[0] | ((unsigned)vals[1] << 16);
        pk.y = (unsigned)vals[2] | ((unsigned)vals[3] << 16);
        pk.z = (unsigned)vals[4] | ((unsigned)vals[5] << 16);
        pk.w = (unsigned)vals[6] | ((unsigned)vals[7] << 16);
        *(uint4*)&Vt[((size_t)h * HD + d) * N_SEQ + n0 + nb] = pk;
    }
}

// ------------------------------------------------------- polynomial attention
// Qh,Kh: [NH][N_SEQ][HD], Vt: [NH][HD][N_SEQ]. O: [N_SEQ][EDIM] bf16 (n-major).
__launch_bounds__(256, 2)
__global__ void k_attn(const unsigned short* __restrict__ Qh,
                       const unsigned short* __restrict__ Kh,
                       const unsigned short* __restrict__ Vt,
                       unsigned short* __restrict__ O) {
    __shared__ unsigned short pool[64 * 136 + 2 * 128 * 72];  // Ks|Vs|Ps, reused as Cs
    unsigned short* Ks = pool;                    // [64][136]
    unsigned short* Vs = pool + 64 * 136;         // [128][72]
    unsigned short* Ps = pool + 64 * 136 + 128 * 72; // [128][72]

    const int h = blockIdx.y;
    const int qb = gridDim.x - 1 - blockIdx.x;   // heavy blocks first
    const int q0 = qb * 128;
    const int t = threadIdx.x;
    const int wave = t >> 6, lane = t & 63;
    const int wm = wave >> 1, wn = wave & 1;
    const int lg = lane >> 4, lr = lane & 15;

    // Q fragments in registers (wave's 64 queries x 128 d)
    bf16x8 qf[4][4];
    #pragma unroll
    for (int mi = 0; mi < 4; ++mi)
        #pragma unroll
        for (int kk = 0; kk < 4; ++kk)
            qf[mi][kk] = *(const bf16x8*)&Qh[((size_t)h * N_SEQ + q0 + wm * 64 + mi * 16 + lr) * HD + kk * 32 + lg * 8];

    f32x4 acc[4][4];
    #pragma unroll
    for (int i = 0; i < 4; ++i)
        #pragma unroll
        for (int j = 0; j < 4; ++j) acc[i][j] = f32x4{0.f, 0.f, 0.f, 0.f};
    f32x4 accd[4];
    #pragma unroll
    for (int i = 0; i < 4; ++i) accd[i] = f32x4{0.f, 0.f, 0.f, 0.f};

    // ones B-fragment: V[k][col]=1 for col==0 -> row-sum in output col 0
    bf16x8 onesf;
    {
        short ov = (lr == 0) ? (short)0x3F80 : (short)0;
        #pragma unroll
        for (int j = 0; j < 8; ++j) onesf[j] = ov;
    }

    const int nkb = 2 * qb + 2;
    for (int kb = 0; kb < nkb; ++kb) {
        const int k0 = kb * 64;
        uint4 kr[4], vr[4];
        #pragma unroll
        for (int i = 0; i < 4; ++i) {
            int ch = i * 256 + t;
            { int r = ch >> 4, d0 = (ch & 15) * 8;
              kr[i] = *(const uint4*)&Kh[((size_t)h * N_SEQ + k0 + r) * HD + d0]; }
            { int d = ch >> 3, n8 = (ch & 7) * 8;
              vr[i] = *(const uint4*)&Vt[((size_t)h * HD + d) * N_SEQ + k0 + n8]; }
        }
        __syncthreads();   // previous PV reads done
        #pragma unroll
        for (int i = 0; i < 4; ++i) {
            int ch = i * 256 + t;
            { int r = ch >> 4, d0 = (ch & 15) * 8; *(uint4*)&Ks[r * 136 + d0] = kr[i]; }
            { int d = ch >> 3, n8 = (ch & 7) * 8;  *(uint4*)&Vs[d * 72 + n8] = vr[i]; }
        }
        __syncthreads();

        // ---- S = Q K^T, mask, ^4, write P to LDS
        bf16x8 kf[2][4];
        #pragma unroll
        for (int ni = 0; ni < 2; ++ni)
            #pragma unroll
            for (int kk = 0; kk < 4; ++kk)
                kf[ni][kk] = *(const bf16x8*)&Ks[(wn * 32 + ni * 16 + lr) * 136 + kk * 32 + lg * 8];
        #pragma unroll
        for (int mi = 0; mi < 4; ++mi) {
            f32x4 sa0 = f32x4{0.f, 0.f, 0.f, 0.f};
            f32x4 sa1 = f32x4{0.f, 0.f, 0.f, 0.f};
            #pragma unroll
            for (int kk = 0; kk < 4; ++kk) {
                sa0 = __builtin_amdgcn_mfma_f32_16x16x32_bf16(qf[mi][kk], kf[0][kk], sa0, 0, 0, 0);
                sa1 = __builtin_amdgcn_mfma_f32_16x16x32_bf16(qf[mi][kk], kf[1][kk], sa1, 0, 0, 0);
            }
            int gk0 = k0 + wn * 32 + lr;
            int gk1 = gk0 + 16;
            #pragma unroll
            for (int r = 0; r < 4; ++r) {
                int rowl = wm * 64 + mi * 16 + lg * 4 + r;
                int gq = q0 + rowl;
                float s0 = sa0[r], s1 = sa1[r];
                float t0 = s0 * s0, t1 = s1 * s1;
                float p0 = (gk0 <= gq) ? t0 * t0 : 0.0f;
                float p1 = (gk1 <= gq) ? t1 * t1 : 0.0f;
                Ps[rowl * 72 + wn * 32 + lr]      = f2bf(p0);
                Ps[rowl * 72 + wn * 32 + 16 + lr] = f2bf(p1);
            }
        }
        __syncthreads();   // P visible to all waves

        // ---- O += P V,  denom += P * ones
        #pragma unroll
        for (int kk = 0; kk < 2; ++kk) {
            bf16x8 pf[4], vf[4];
            #pragma unroll
            for (int mi = 0; mi < 4; ++mi)
                pf[mi] = *(const bf16x8*)&Ps[(wm * 64 + mi * 16 + lr) * 72 + kk * 32 + lg * 8];
            #pragma unroll
            for (int ni = 0; ni < 4; ++ni)
                vf[ni] = *(const bf16x8*)&Vs[(wn * 64 + ni * 16 + lr) * 72 + kk * 32 + lg * 8];
            #pragma unroll
            for (int mi = 0; mi < 4; ++mi) {
                #pragma unroll
                for (int ni = 0; ni < 4; ++ni)
                    acc[mi][ni] = __builtin_amdgcn_mfma_f32_16x16x32_bf16(pf[mi], vf[ni], acc[mi][ni], 0, 0, 0);
                accd[mi] = __builtin_amdgcn_mfma_f32_16x16x32_bf16(pf[mi], onesf, accd[mi], 0, 0, 0);
            }
        }
    }

    // epilogue: out = acc / denom, staged via LDS for coalesced global writes
    __syncthreads();
    unsigned short* Cs = pool;   // [128][128]
    #pragma unroll
    for (int mi = 0; mi < 4; ++mi) {
        #pragma unroll
        for (int r = 0; r < 4; ++r) {
            float dv = __shfl(accd[mi][r], lane & 48);  // from lane lg*16 (col 0)
            float rinv = 1.0f / dv;
            int rowl = wm * 64 + mi * 16 + lg * 4 + r;
            #pragma unroll
            for (int ni = 0; ni < 4; ++ni)
                Cs[rowl * 128 + wn * 64 + ni * 16 + lr] = f2bf(acc[mi][ni][r] * rinv);
        }
    }
    __syncthreads();
    #pragma unroll
    for (int i = 0; i < 8; ++i) {
        int ch = i * 256 + t;             // 2048 chunks of 8 shorts
        int row = ch >> 4, c8 = (ch & 15) * 8;
        *(uint4*)&O[(size_t)(q0 + row) * EDIM + h * HD + c8] = *(const uint4*)&Cs[row * 128 + c8];
    }
}

// ---------------------------------------------------------------- launch
extern "C" void kernel_launch(void* const* d_in, const int* in_sizes, int n_in,
                              void* d_out, int out_size, void* d_ws, size_t ws_size,
                              hipStream_t stream) {
    const float* x        = (const float*)d_in[0];
    const float* w_qkv    = (const float*)d_in[1];
    const float* w_out    = (const float*)d_in[2];
    const float* ln_scale = (const float*)d_in[3];
    const float* ln_bias  = (const float*)d_in[4];

    if (ws_size < 134217728u) return;  // need 128 MiB

    char* ws = (char*)d_ws;
    // lifetime-aliased layout (128 MiB total):
    unsigned short* xb    = (unsigned short*)(ws);              // 16 MiB; reused as attnO
    unsigned short* wqkvT = (unsigned short*)(ws + 16777216);   // 24 MiB; reused as Qh
    unsigned short* woutT = (unsigned short*)(ws + 41943040);   //  8 MiB
    unsigned short* proj  = (unsigned short*)(ws + 50331648);   // 48 MiB
    unsigned short* Kh    = (unsigned short*)(ws + 100663296);  // 16 MiB
    unsigned short* Vt    = (unsigned short*)(ws + 117440512);  // 16 MiB
    unsigned short* Qh    = wqkvT;   // alias: w_qkvT dead after GEMM1
    unsigned short* attnO = xb;      // alias: xb dead after GEMM1

    k_convert_x<<<2048, 256, 0, stream>>>(x, xb, (N_SEQ * EDIM) / 4);
    k_transpose_f32_bf16<<<dim3(3 * EDIM / 64, EDIM / 64), 256, 0, stream>>>(w_qkv, wqkvT, EDIM, 3 * EDIM);
    k_transpose_f32_bf16<<<dim3(EDIM / 64, EDIM / 64), 256, 0, stream>>>(w_out, woutT, EDIM, EDIM);
    k_gemm_bt<0><<<dim3(3 * EDIM / 128, N_SEQ / 128), 256, 0, stream>>>(xb, wqkvT, proj, N_SEQ, 3 * EDIM, EDIM);
    k_ropeln<<<N_SEQ, 256, 0, stream>>>(proj, ln_scale, ln_bias, Qh, Kh);
    k_vtrans<<<dim3(N_SEQ / 64, NH), 256, 0, stream>>>(proj, Vt);
    k_attn<<<dim3(N_SEQ / 128, NH), 256, 0, stream>>>(Qh, Kh, Vt, attnO);
    k_gemm_bt<1><<<dim3(EDIM / 128, N_SEQ / 128), 256, 0, stream>>>(attnO, woutT, (float*)d_out, N_SEQ, EDIM, EDIM);
}